// Round 1
// 208.657 us; speedup vs baseline: 1.0343x; 1.0343x over previous
//
#include <hip/hip_runtime.h>
#include <math.h>

#define S_LEN 2048
#define DIM   512
#define M_TOT 8192
#define NCH   (S_LEN / 64)

typedef __attribute__((ext_vector_type(8))) short bf16x8;
typedef __attribute__((ext_vector_type(4))) short bf16x4;
typedef __attribute__((ext_vector_type(4))) float f32x4;

#define MFMA(a, b, c) __builtin_amdgcn_mfma_f32_16x16x32_bf16((a), (b), (c), 0, 0, 0)

// log2(e)/8 : baked into Wq so attention scores arrive as log2(e)*s/8,
// letting softmax use exp2 directly (exp(relu(s)/8) == exp2(relu(s'))).
#define QSCALE 0.18033688011112042f

__device__ __forceinline__ short f2b(float x) {
    union { float f; unsigned u; } v; v.f = x;
    unsigned r = v.u + 0x7FFFu + ((v.u >> 16) & 1u);   // RNE
    return (short)(r >> 16);
}

// packed f32x2 -> bf16x2 (RNE), single VOP3
__device__ __forceinline__ unsigned cvtpk(float a, float b) {
    unsigned r;
    asm("v_cvt_pk_bf16_f32 %0, %1, %2" : "=v"(r) : "v"(a), "v"(b));
    return r;
}

__device__ __forceinline__ bf16x8 cvt8(float4 lo, float4 hi) {
    union { unsigned u[4]; bf16x8 v; } o;
    o.u[0] = cvtpk(lo.x, lo.y);
    o.u[1] = cvtpk(lo.z, lo.w);
    o.u[2] = cvtpk(hi.x, hi.y);
    o.u[3] = cvtpk(hi.z, hi.w);
    return o.v;
}

__device__ __forceinline__ float fast_exp2(float x) {
#if __has_builtin(__builtin_amdgcn_exp2f)
    return __builtin_amdgcn_exp2f(x);
#else
    return __expf(x * 0.693147180559945f);   // exp(x*ln2) == 2^x
#endif
}

// ---------------------------------------------------------------------------
// Wt[n][k] bf16 = transpose+convert of W[k][n] f32. 64x64 tiles.
// Wq additionally scaled by QSCALE (see above).
// ---------------------------------------------------------------------------
__global__ __launch_bounds__(256) void prep_wt(const float* Wq, const float* Wk, const float* Wo,
                                               short* Wtq, short* Wtk, short* Wto) {
    const int zi = blockIdx.z;
    const float* W = zi == 0 ? Wq : zi == 1 ? Wk : Wo;
    short*      Wt = zi == 0 ? Wtq : zi == 1 ? Wtk : Wto;
    const float sc = zi == 0 ? QSCALE : 1.0f;
    __shared__ short Ts[64 * 72];
    const int t = threadIdx.x;
    const int k0 = blockIdx.x * 64, n0 = blockIdx.y * 64;
    #pragma unroll
    for (int it = 0; it < 4; ++it) {
        const int r = (t >> 4) + 16 * it;
        const int cq = t & 15;
        float4 v = *(const float4*)&W[(size_t)(k0 + r) * DIM + n0 + cq * 4];
        Ts[(4 * cq + 0) * 72 + r] = f2b(v.x * sc);
        Ts[(4 * cq + 1) * 72 + r] = f2b(v.y * sc);
        Ts[(4 * cq + 2) * 72 + r] = f2b(v.z * sc);
        Ts[(4 * cq + 3) * 72 + r] = f2b(v.w * sc);
    }
    __syncthreads();
    #pragma unroll
    for (int it = 0; it < 2; ++it) {
        const int n = (t >> 3) + 32 * it;
        const int sg = t & 7;
        *(bf16x8*)&Wt[(size_t)(n0 + n) * DIM + k0 + sg * 8] = *(const bf16x8*)&Ts[n * 72 + sg * 8];
    }
}

// ---------------------------------------------------------------------------
// Projection GEMMs (fused 3): 128x128 tile, BK=32, 4 waves (2x2, each 64x64).
// A is read as fp32 (X/Y/Z) and converted to bf16 during staging (cvt kernel
// fused away). B comes pre-transposed bf16.
// zi==2 (V) is stored TRANSPOSED per (b,h): Vt[((b*8+h)*64+hd)*2048 + s].
// ---------------------------------------------------------------------------
__global__ __launch_bounds__(256) void proj_gemm(const float* __restrict__ X,
                                                 const float* __restrict__ Y,
                                                 const float* __restrict__ Z,
                                                 const short* __restrict__ Wtq,
                                                 const short* __restrict__ Wtk,
                                                 const short* __restrict__ Wto,
                                                 short* __restrict__ Qb,
                                                 short* __restrict__ Kb,
                                                 short* __restrict__ Vt) {
    const int zi = blockIdx.z;
    const float* A  = zi == 0 ? X : zi == 1 ? Y : Z;
    const short* Bw = zi == 0 ? Wtq : zi == 1 ? Wtk : Wto;

    __shared__ short As[128 * 40];
    __shared__ short Bs[128 * 40];
    const int tid = threadIdx.x;
    const int w = tid >> 6, ln = tid & 63, l15 = ln & 15, quad = ln >> 4;
    const int m0 = blockIdx.x * 128, n0 = blockIdx.y * 128;
    const int wm = (w & 1) * 64, wn = (w >> 1) * 64;

    const int r0 = tid >> 2, r1 = r0 + 64;
    const int sg = tid & 3;
    const float* ap0 = A  + (size_t)(m0 + r0) * DIM + sg * 8;
    const float* ap1 = A  + (size_t)(m0 + r1) * DIM + sg * 8;
    const short* bp0 = Bw + (size_t)(n0 + r0) * DIM + sg * 8;
    const short* bp1 = Bw + (size_t)(n0 + r1) * DIM + sg * 8;

    float4 a0l = *(const float4*)ap0, a0h = *(const float4*)(ap0 + 4);
    float4 a1l = *(const float4*)ap1, a1h = *(const float4*)(ap1 + 4);
    bf16x8 b0 = *(const bf16x8*)bp0, b1 = *(const bf16x8*)bp1;

    f32x4 acc[4][4] = {};

    for (int k0 = 0; k0 < DIM; k0 += 32) {
        __syncthreads();
        *(bf16x8*)&As[r0 * 40 + sg * 8] = cvt8(a0l, a0h);
        *(bf16x8*)&As[r1 * 40 + sg * 8] = cvt8(a1l, a1h);
        *(bf16x8*)&Bs[r0 * 40 + sg * 8] = b0;
        *(bf16x8*)&Bs[r1 * 40 + sg * 8] = b1;
        __syncthreads();
        const int kn = (k0 + 32 < DIM) ? k0 + 32 : 0;
        a0l = *(const float4*)(ap0 + kn); a0h = *(const float4*)(ap0 + kn + 4);
        a1l = *(const float4*)(ap1 + kn); a1h = *(const float4*)(ap1 + kn + 4);
        b0 = *(const bf16x8*)(bp0 + kn); b1 = *(const bf16x8*)(bp1 + kn);

        bf16x8 af[4], bf[4];
        #pragma unroll
        for (int mf = 0; mf < 4; ++mf) af[mf] = *(const bf16x8*)&As[(wm + 16 * mf + l15) * 40 + quad * 8];
        #pragma unroll
        for (int nf = 0; nf < 4; ++nf) bf[nf] = *(const bf16x8*)&Bs[(wn + 16 * nf + l15) * 40 + quad * 8];
        #pragma unroll
        for (int mf = 0; mf < 4; ++mf)
            #pragma unroll
            for (int nf = 0; nf < 4; ++nf)
                acc[mf][nf] = MFMA(af[mf], bf[nf], acc[mf][nf]);
    }

    if (zi < 2) {
        short* C = zi == 0 ? Qb : Kb;
        #pragma unroll
        for (int mf = 0; mf < 4; ++mf)
            #pragma unroll
            for (int nf = 0; nf < 4; ++nf)
                #pragma unroll
                for (int r = 0; r < 4; ++r)
                    C[(size_t)(m0 + wm + 16 * mf + 4 * quad + r) * DIM + n0 + wn + 16 * nf + l15] =
                        f2b(acc[mf][nf][r]);
    } else {
        #pragma unroll
        for (int mf = 0; mf < 4; ++mf)
            #pragma unroll
            for (int nf = 0; nf < 4; ++nf) {
                const int col = n0 + wn + 16 * nf + l15;
                const int h = col >> 6, hd = col & 63;
                const int row0_ = m0 + wm + 16 * mf + 4 * quad;
                const int bb = row0_ >> 11, s0 = row0_ & 2047;
                bf16x4 o = { f2b(acc[mf][nf][0]), f2b(acc[mf][nf][1]),
                             f2b(acc[mf][nf][2]), f2b(acc[mf][nf][3]) };
                *(bf16x4*)&Vt[((size_t)((bb * 8 + h) * 64 + hd)) * S_LEN + s0] = o;
            }
    }
}

// ---------------------------------------------------------------------------
// Final GEMM: fp32 out = Ob_bf16 @ Wto^T. Same 128x128 structure.
// ---------------------------------------------------------------------------
__global__ __launch_bounds__(256) void out_gemm(const short* __restrict__ Ob,
                                                const short* __restrict__ Wto,
                                                float* __restrict__ Cout) {
    __shared__ short As[128 * 40];
    __shared__ short Bs[128 * 40];
    const int tid = threadIdx.x;
    const int w = tid >> 6, ln = tid & 63, l15 = ln & 15, quad = ln >> 4;
    const int m0 = blockIdx.x * 128, n0 = blockIdx.y * 128;
    const int wm = (w & 1) * 64, wn = (w >> 1) * 64;

    const int r0 = tid >> 2, r1 = r0 + 64;
    const int sg = tid & 3;
    const short* ap0 = Ob  + (size_t)(m0 + r0) * DIM + sg * 8;
    const short* ap1 = Ob  + (size_t)(m0 + r1) * DIM + sg * 8;
    const short* bp0 = Wto + (size_t)(n0 + r0) * DIM + sg * 8;
    const short* bp1 = Wto + (size_t)(n0 + r1) * DIM + sg * 8;

    bf16x8 a0 = *(const bf16x8*)ap0, a1 = *(const bf16x8*)ap1;
    bf16x8 b0 = *(const bf16x8*)bp0, b1 = *(const bf16x8*)bp1;

    f32x4 acc[4][4] = {};

    for (int k0 = 0; k0 < DIM; k0 += 32) {
        __syncthreads();
        *(bf16x8*)&As[r0 * 40 + sg * 8] = a0;
        *(bf16x8*)&As[r1 * 40 + sg * 8] = a1;
        *(bf16x8*)&Bs[r0 * 40 + sg * 8] = b0;
        *(bf16x8*)&Bs[r1 * 40 + sg * 8] = b1;
        __syncthreads();
        const int kn = (k0 + 32 < DIM) ? k0 + 32 : 0;
        a0 = *(const bf16x8*)(ap0 + kn); a1 = *(const bf16x8*)(ap1 + kn);
        b0 = *(const bf16x8*)(bp0 + kn); b1 = *(const bf16x8*)(bp1 + kn);

        bf16x8 af[4], bf[4];
        #pragma unroll
        for (int mf = 0; mf < 4; ++mf) af[mf] = *(const bf16x8*)&As[(wm + 16 * mf + l15) * 40 + quad * 8];
        #pragma unroll
        for (int nf = 0; nf < 4; ++nf) bf[nf] = *(const bf16x8*)&Bs[(wn + 16 * nf + l15) * 40 + quad * 8];
        #pragma unroll
        for (int mf = 0; mf < 4; ++mf)
            #pragma unroll
            for (int nf = 0; nf < 4; ++nf)
                acc[mf][nf] = MFMA(af[mf], bf[nf], acc[mf][nf]);
    }
    #pragma unroll
    for (int mf = 0; mf < 4; ++mf)
        #pragma unroll
        for (int nf = 0; nf < 4; ++nf)
            #pragma unroll
            for (int r = 0; r < 4; ++r)
                Cout[(size_t)(m0 + wm + 16 * mf + 4 * quad + r) * DIM + n0 + wn + 16 * nf + l15] =
                    acc[mf][nf][r];
}

// ---------------------------------------------------------------------------
// Attention: 4 waves x 32q = 128q per block, per (b,h). Double-buffered K/V
// LDS (1 barrier/chunk). V arrives pre-transposed (Vt) -> natural b128
// staging. Scores arrive pre-scaled by log2(e)/8 (baked into Wq), so
// e = exp2(max(s,0)) — 2 VALU ops/element. E packed via v_cvt_pk_bf16_f32.
// XCD-chunked swizzle: all 16 q-tiles of a (b,h) land on one XCD (K/V L2 hit).
// ---------------------------------------------------------------------------
__global__ __launch_bounds__(256) void attn_mfma(const short* __restrict__ Qb,
                                                 const short* __restrict__ Kb,
                                                 const short* __restrict__ Vtg,
                                                 short* __restrict__ Ob) {
    __shared__ short Ks[2][64 * 72];
    __shared__ short Vs[2][64 * 72];
    __shared__ short Es[4][32 * 72];

    const int tid = threadIdx.x;
    const int w = tid >> 6, ln = tid & 63, l15 = ln & 15, quad = ln >> 4;

    // XCD-chunked bijective swizzle (512 blocks, 8 XCDs, 64 per XCD):
    // blocks with the same lin%8 (same XCD) get consecutive swz -> same bh group.
    const int lin = blockIdx.y * 16 + blockIdx.x;
    const int swz = ((lin & 7) << 6) + (lin >> 3);
    const int qt0 = (swz & 15) * 128;
    const int bh  = swz >> 4;
    const int b = bh >> 3, h = bh & 7;
    const size_t tokbase = (size_t)b * S_LEN;

    // resident Q fragments: wave w covers q rows [qt0+32w, qt0+32w+32)
    bf16x8 qf[2][2];
    #pragma unroll
    for (int nf = 0; nf < 2; ++nf)
        #pragma unroll
        for (int ks = 0; ks < 2; ++ks)
            qf[nf][ks] = *(const bf16x8*)&Qb[(tokbase + qt0 + 32 * w + 16 * nf + l15) * DIM +
                                             h * 64 + 32 * ks + 8 * quad];

    const int srow = tid >> 3, ssg = tid & 7;    // srow 0..31
    const short* kbase = Kb  + (tokbase + srow) * DIM + h * 64 + ssg * 8;
    const short* vbase = Vtg + ((size_t)bh * 64 + srow) * S_LEN + ssg * 8;

    bf16x8 k0r, k1r, v0r, v1r;

    f32x4 oacc[2][4] = {};
    f32x4 d4[2] = {};                 // 4-wide partial denominators (break add chain)

    // prologue: chunk0 -> buf0; prefetch chunk1 regs
    {
        k0r = *(const bf16x8*)kbase;
        k1r = *(const bf16x8*)(kbase + (size_t)32 * DIM);
        v0r = *(const bf16x8*)vbase;
        v1r = *(const bf16x8*)(vbase + (size_t)32 * S_LEN);
        *(bf16x8*)&Ks[0][srow * 72 + ssg * 8] = k0r;
        *(bf16x8*)&Ks[0][(srow + 32) * 72 + ssg * 8] = k1r;
        *(bf16x8*)&Vs[0][srow * 72 + ssg * 8] = v0r;
        *(bf16x8*)&Vs[0][(srow + 32) * 72 + ssg * 8] = v1r;
        k0r = *(const bf16x8*)(kbase + (size_t)64 * DIM);
        k1r = *(const bf16x8*)(kbase + (size_t)96 * DIM);
        v0r = *(const bf16x8*)(vbase + 64);
        v1r = *(const bf16x8*)(vbase + (size_t)32 * S_LEN + 64);
    }
    __syncthreads();

    for (int kc = 0; kc < NCH; ++kc) {
        const int cur = kc & 1;
        if (kc + 1 < NCH) {     // stage chunk kc+1 (regs) into other buffer
            *(bf16x8*)&Ks[cur ^ 1][srow * 72 + ssg * 8] = k0r;
            *(bf16x8*)&Ks[cur ^ 1][(srow + 32) * 72 + ssg * 8] = k1r;
            *(bf16x8*)&Vs[cur ^ 1][srow * 72 + ssg * 8] = v0r;
            *(bf16x8*)&Vs[cur ^ 1][(srow + 32) * 72 + ssg * 8] = v1r;
        }
        if (kc + 2 < NCH) {     // prefetch chunk kc+2 into regs
            const size_t ko = (size_t)(kc + 2) * 64 * DIM;
            const size_t vo = (size_t)(kc + 2) * 64;
            k0r = *(const bf16x8*)(kbase + ko);
            k1r = *(const bf16x8*)(kbase + ko + (size_t)32 * DIM);
            v0r = *(const bf16x8*)(vbase + vo);
            v1r = *(const bf16x8*)(vbase + vo + (size_t)32 * S_LEN);
        }

        // ---- phase 1: S^T[key][q] = K * Q^T ----
        f32x4 sacc[4][2];
        __builtin_amdgcn_s_setprio(1);
        #pragma unroll
        for (int mf = 0; mf < 4; ++mf) {
            bf16x8 ka = *(const bf16x8*)&Ks[cur][(16 * mf + l15) * 72 + 8 * quad];
            bf16x8 kb = *(const bf16x8*)&Ks[cur][(16 * mf + l15) * 72 + 32 + 8 * quad];
            #pragma unroll
            for (int nf = 0; nf < 2; ++nf) {
                f32x4 s = {0.f, 0.f, 0.f, 0.f};
                s = MFMA(ka, qf[nf][0], s);
                s = MFMA(kb, qf[nf][1], s);
                sacc[mf][nf] = s;
            }
        }
        __builtin_amdgcn_s_setprio(0);

        // ---- e = exp2(max(s,0)) -> Es (per-wave, no barrier) ----
        short* Esw = &Es[w][0];
        #pragma unroll
        for (int mf = 0; mf < 4; ++mf)
            #pragma unroll
            for (int nf = 0; nf < 2; ++nf) {
                const float e0 = fast_exp2(fmaxf(sacc[mf][nf][0], 0.f));
                const float e1 = fast_exp2(fmaxf(sacc[mf][nf][1], 0.f));
                const float e2 = fast_exp2(fmaxf(sacc[mf][nf][2], 0.f));
                const float e3 = fast_exp2(fmaxf(sacc[mf][nf][3], 0.f));
                d4[nf][0] += e0; d4[nf][1] += e1;
                d4[nf][2] += e2; d4[nf][3] += e3;
                uint2 p;
                p.x = cvtpk(e0, e1);
                p.y = cvtpk(e2, e3);
                *(uint2*)&Esw[(16 * nf + l15) * 72 + 16 * mf + 4 * quad] = p;
            }

        // ---- phase 2: O[q][hd] += E * V ----
        bf16x8 e00 = *(const bf16x8*)&Esw[l15 * 72 + 8 * quad];
        bf16x8 e01 = *(const bf16x8*)&Esw[l15 * 72 + 32 + 8 * quad];
        bf16x8 e10 = *(const bf16x8*)&Esw[(16 + l15) * 72 + 8 * quad];
        bf16x8 e11 = *(const bf16x8*)&Esw[(16 + l15) * 72 + 32 + 8 * quad];
        __builtin_amdgcn_s_setprio(1);
        #pragma unroll
        for (int nf2 = 0; nf2 < 4; ++nf2) {
            bf16x8 vf0 = *(const bf16x8*)&Vs[cur][(16 * nf2 + l15) * 72 + 8 * quad];
            bf16x8 vf1 = *(const bf16x8*)&Vs[cur][(16 * nf2 + l15) * 72 + 32 + 8 * quad];
            oacc[0][nf2] = MFMA(e00, vf0, oacc[0][nf2]);
            oacc[0][nf2] = MFMA(e01, vf1, oacc[0][nf2]);
            oacc[1][nf2] = MFMA(e10, vf0, oacc[1][nf2]);
            oacc[1][nf2] = MFMA(e11, vf1, oacc[1][nf2]);
        }
        __builtin_amdgcn_s_setprio(0);
        __syncthreads();
    }

    // ---- denominators: horizontal sum of 4-wide partials, then quad shfl
    float dsum[2];
    #pragma unroll
    for (int nf = 0; nf < 2; ++nf) {
        dsum[nf] = (d4[nf][0] + d4[nf][1]) + (d4[nf][2] + d4[nf][3]);
        dsum[nf] += __shfl_xor(dsum[nf], 16);
        dsum[nf] += __shfl_xor(dsum[nf], 32);
    }
    const float dinv0 = 1.0f / dsum[0];
    const float dinv1 = 1.0f / dsum[1];

    // ---- normalize + store bf16 ----
    #pragma unroll
    for (int mf2 = 0; mf2 < 2; ++mf2) {
        const float dv = mf2 ? dinv1 : dinv0;
        #pragma unroll
        for (int r = 0; r < 4; ++r) {
            const float di = __shfl(dv, 4 * quad + r);   // lane l15=4q+r holds row's dinv
            const size_t rowaddr = (tokbase + qt0 + 32 * w + 16 * mf2 + 4 * quad + r) * DIM + h * 64;
            #pragma unroll
            for (int nf2 = 0; nf2 < 4; ++nf2)
                Ob[rowaddr + 16 * nf2 + l15] = f2b(oacc[mf2][nf2][r] * di);
        }
    }
}

// ---------------------------------------------------------------------------
extern "C" void kernel_launch(void* const* d_in, const int* in_sizes, int n_in,
                              void* d_out, int out_size, void* d_ws, size_t ws_size,
                              hipStream_t stream) {
    const float* X  = (const float*)d_in[0];
    const float* Y  = (const float*)d_in[1];
    const float* Z  = (const float*)d_in[2];
    const float* Wq = (const float*)d_in[3];
    const float* Wk = (const float*)d_in[4];
    // d_in[5] = Wv dead in reference forward
    const float* Wo = (const float*)d_in[6];

    char* p = (char*)d_ws;
    const size_t MD = (size_t)M_TOT * DIM;
    short* Qb  = (short*)p; p += MD * 2;
    short* Kb  = (short*)p; p += MD * 2;
    short* Vt  = (short*)p; p += MD * 2;
    short* Ob  = (short*)p; p += MD * 2;
    short* Wtq = (short*)p; p += (size_t)DIM * DIM * 2;
    short* Wtk = (short*)p; p += (size_t)DIM * DIM * 2;
    short* Wto = (short*)p; p += (size_t)DIM * DIM * 2;

    prep_wt<<<dim3(8, 8, 3), 256, 0, stream>>>(Wq, Wk, Wo, Wtq, Wtk, Wto);
    proj_gemm<<<dim3(64, 4, 3), 256, 0, stream>>>(X, Y, Z, Wtq, Wtk, Wto, Qb, Kb, Vt);
    attn_mfma<<<dim3(16, 32), 256, 0, stream>>>(Qb, Kb, Vt, Ob);
    out_gemm<<<dim3(64, 4), 256, 0, stream>>>(Ob, Wto, (float*)d_out);
}

// Round 2
// 203.832 us; speedup vs baseline: 1.0588x; 1.0237x over previous
//
#include <hip/hip_runtime.h>
#include <math.h>

#define S_LEN 2048
#define DIM   512
#define M_TOT 8192
#define NCH   (S_LEN / 64)

typedef __attribute__((ext_vector_type(8))) short bf16x8;
typedef __attribute__((ext_vector_type(4))) short bf16x4;
typedef __attribute__((ext_vector_type(4))) float f32x4;

#define MFMA(a, b, c) __builtin_amdgcn_mfma_f32_16x16x32_bf16((a), (b), (c), 0, 0, 0)

// log2(e)/8 : baked into Wq so attention scores arrive as log2(e)*s/8,
// letting softmax use exp2 directly (exp(relu(s)/8) == exp2(relu(s'))).
#define QSCALE 0.18033688011112042f

__device__ __forceinline__ short f2b(float x) {
    union { float f; unsigned u; } v; v.f = x;
    unsigned r = v.u + 0x7FFFu + ((v.u >> 16) & 1u);   // RNE
    return (short)(r >> 16);
}

// packed f32x2 -> bf16x2 (RNE), single VOP3
__device__ __forceinline__ unsigned cvtpk(float a, float b) {
    unsigned r;
    asm("v_cvt_pk_bf16_f32 %0, %1, %2" : "=v"(r) : "v"(a), "v"(b));
    return r;
}

__device__ __forceinline__ bf16x8 cvt8(float4 lo, float4 hi) {
    union { unsigned u[4]; bf16x8 v; } o;
    o.u[0] = cvtpk(lo.x, lo.y);
    o.u[1] = cvtpk(lo.z, lo.w);
    o.u[2] = cvtpk(hi.x, hi.y);
    o.u[3] = cvtpk(hi.z, hi.w);
    return o.v;
}

__device__ __forceinline__ float fast_exp2(float x) {
#if __has_builtin(__builtin_amdgcn_exp2f)
    return __builtin_amdgcn_exp2f(x);
#else
    return __expf(x * 0.693147180559945f);   // exp(x*ln2) == 2^x
#endif
}

// ---------------------------------------------------------------------------
// Wt[n][k] bf16 = transpose+convert of W[k][n] f32. 64x64 tiles.
// Wq additionally scaled by QSCALE (see above).
// ---------------------------------------------------------------------------
__global__ __launch_bounds__(256) void prep_wt(const float* Wq, const float* Wk, const float* Wo,
                                               short* Wtq, short* Wtk, short* Wto) {
    const int zi = blockIdx.z;
    const float* W = zi == 0 ? Wq : zi == 1 ? Wk : Wo;
    short*      Wt = zi == 0 ? Wtq : zi == 1 ? Wtk : Wto;
    const float sc = zi == 0 ? QSCALE : 1.0f;
    __shared__ short Ts[64 * 72];
    const int t = threadIdx.x;
    const int k0 = blockIdx.x * 64, n0 = blockIdx.y * 64;
    #pragma unroll
    for (int it = 0; it < 4; ++it) {
        const int r = (t >> 4) + 16 * it;
        const int cq = t & 15;
        float4 v = *(const float4*)&W[(size_t)(k0 + r) * DIM + n0 + cq * 4];
        Ts[(4 * cq + 0) * 72 + r] = f2b(v.x * sc);
        Ts[(4 * cq + 1) * 72 + r] = f2b(v.y * sc);
        Ts[(4 * cq + 2) * 72 + r] = f2b(v.z * sc);
        Ts[(4 * cq + 3) * 72 + r] = f2b(v.w * sc);
    }
    __syncthreads();
    #pragma unroll
    for (int it = 0; it < 2; ++it) {
        const int n = (t >> 3) + 32 * it;
        const int sg = t & 7;
        *(bf16x8*)&Wt[(size_t)(n0 + n) * DIM + k0 + sg * 8] = *(const bf16x8*)&Ts[n * 72 + sg * 8];
    }
}

// ---------------------------------------------------------------------------
// Projection GEMMs (fused 3): 128x128 tile, BK=32, 4 waves (2x2, each 64x64).
// A is read as fp32 (X/Y/Z) and converted to bf16 during staging.
// zi==2 (V) is stored TRANSPOSED per (b,h): Vt[((b*8+h)*64+hd)*2048 + s].
// ---------------------------------------------------------------------------
__global__ __launch_bounds__(256) void proj_gemm(const float* __restrict__ X,
                                                 const float* __restrict__ Y,
                                                 const float* __restrict__ Z,
                                                 const short* __restrict__ Wtq,
                                                 const short* __restrict__ Wtk,
                                                 const short* __restrict__ Wto,
                                                 short* __restrict__ Qb,
                                                 short* __restrict__ Kb,
                                                 short* __restrict__ Vt) {
    const int zi = blockIdx.z;
    const float* A  = zi == 0 ? X : zi == 1 ? Y : Z;
    const short* Bw = zi == 0 ? Wtq : zi == 1 ? Wtk : Wto;

    __shared__ short As[128 * 40];
    __shared__ short Bs[128 * 40];
    const int tid = threadIdx.x;
    const int w = tid >> 6, ln = tid & 63, l15 = ln & 15, quad = ln >> 4;
    const int m0 = blockIdx.x * 128, n0 = blockIdx.y * 128;
    const int wm = (w & 1) * 64, wn = (w >> 1) * 64;

    const int r0 = tid >> 2, r1 = r0 + 64;
    const int sg = tid & 3;
    const float* ap0 = A  + (size_t)(m0 + r0) * DIM + sg * 8;
    const float* ap1 = A  + (size_t)(m0 + r1) * DIM + sg * 8;
    const short* bp0 = Bw + (size_t)(n0 + r0) * DIM + sg * 8;
    const short* bp1 = Bw + (size_t)(n0 + r1) * DIM + sg * 8;

    float4 a0l = *(const float4*)ap0, a0h = *(const float4*)(ap0 + 4);
    float4 a1l = *(const float4*)ap1, a1h = *(const float4*)(ap1 + 4);
    bf16x8 b0 = *(const bf16x8*)bp0, b1 = *(const bf16x8*)bp1;

    f32x4 acc[4][4] = {};

    for (int k0 = 0; k0 < DIM; k0 += 32) {
        __syncthreads();
        *(bf16x8*)&As[r0 * 40 + sg * 8] = cvt8(a0l, a0h);
        *(bf16x8*)&As[r1 * 40 + sg * 8] = cvt8(a1l, a1h);
        *(bf16x8*)&Bs[r0 * 40 + sg * 8] = b0;
        *(bf16x8*)&Bs[r1 * 40 + sg * 8] = b1;
        __syncthreads();
        const int kn = (k0 + 32 < DIM) ? k0 + 32 : 0;
        a0l = *(const float4*)(ap0 + kn); a0h = *(const float4*)(ap0 + kn + 4);
        a1l = *(const float4*)(ap1 + kn); a1h = *(const float4*)(ap1 + kn + 4);
        b0 = *(const bf16x8*)(bp0 + kn); b1 = *(const bf16x8*)(bp1 + kn);

        bf16x8 af[4], bf[4];
        #pragma unroll
        for (int mf = 0; mf < 4; ++mf) af[mf] = *(const bf16x8*)&As[(wm + 16 * mf + l15) * 40 + quad * 8];
        #pragma unroll
        for (int nf = 0; nf < 4; ++nf) bf[nf] = *(const bf16x8*)&Bs[(wn + 16 * nf + l15) * 40 + quad * 8];
        #pragma unroll
        for (int mf = 0; mf < 4; ++mf)
            #pragma unroll
            for (int nf = 0; nf < 4; ++nf)
                acc[mf][nf] = MFMA(af[mf], bf[nf], acc[mf][nf]);
    }

    if (zi < 2) {
        short* C = zi == 0 ? Qb : Kb;
        #pragma unroll
        for (int mf = 0; mf < 4; ++mf)
            #pragma unroll
            for (int nf = 0; nf < 4; ++nf)
                #pragma unroll
                for (int r = 0; r < 4; ++r)
                    C[(size_t)(m0 + wm + 16 * mf + 4 * quad + r) * DIM + n0 + wn + 16 * nf + l15] =
                        f2b(acc[mf][nf][r]);
    } else {
        #pragma unroll
        for (int mf = 0; mf < 4; ++mf)
            #pragma unroll
            for (int nf = 0; nf < 4; ++nf) {
                const int col = n0 + wn + 16 * nf + l15;
                const int h = col >> 6, hd = col & 63;
                const int row0_ = m0 + wm + 16 * mf + 4 * quad;
                const int bb = row0_ >> 11, s0 = row0_ & 2047;
                bf16x4 o = { f2b(acc[mf][nf][0]), f2b(acc[mf][nf][1]),
                             f2b(acc[mf][nf][2]), f2b(acc[mf][nf][3]) };
                *(bf16x4*)&Vt[((size_t)((bb * 8 + h) * 64 + hd)) * S_LEN + s0] = o;
            }
    }
}

// ---------------------------------------------------------------------------
// Final GEMM: fp32 out = Ob_bf16 @ Wto^T. 64x64 tiles, 1024 blocks
// (4 blocks/CU, 16 waves/CU — old 128x128 grid was 1 block/CU).
// Swizzle keeps the 8 N-tiles sharing an A-panel on one XCD.
// ---------------------------------------------------------------------------
__global__ __launch_bounds__(256) void out_gemm(const short* __restrict__ Ob,
                                                const short* __restrict__ Wto,
                                                float* __restrict__ Cout) {
    __shared__ short As[64 * 40];
    __shared__ short Bs[64 * 40];
    const int tid = threadIdx.x;
    const int w = tid >> 6, ln = tid & 63, l15 = ln & 15, quad = ln >> 4;

    const int f = blockIdx.x;
    const int swz = ((f & 7) << 7) | (f >> 3);      // bijective, 1024 blocks
    const int m0 = (swz >> 3) * 64, n0 = (swz & 7) * 64;
    const int wm = (w & 1) * 32, wn = (w >> 1) * 32;

    const int row = tid >> 2;         // 0..63
    const int sg = tid & 3;           // k sub-offset
    const short* ap = Ob  + (size_t)(m0 + row) * DIM + sg * 8;
    const short* bp = Wto + (size_t)(n0 + row) * DIM + sg * 8;

    bf16x8 a0 = *(const bf16x8*)ap, b0 = *(const bf16x8*)bp;

    f32x4 acc[2][2] = {};

    for (int k0 = 0; k0 < DIM; k0 += 32) {
        __syncthreads();
        *(bf16x8*)&As[row * 40 + sg * 8] = a0;
        *(bf16x8*)&Bs[row * 40 + sg * 8] = b0;
        __syncthreads();
        const int kn = (k0 + 32 < DIM) ? k0 + 32 : 0;
        a0 = *(const bf16x8*)(ap + kn); b0 = *(const bf16x8*)(bp + kn);

        bf16x8 af[2], bf[2];
        #pragma unroll
        for (int mf = 0; mf < 2; ++mf) af[mf] = *(const bf16x8*)&As[(wm + 16 * mf + l15) * 40 + quad * 8];
        #pragma unroll
        for (int nf = 0; nf < 2; ++nf) bf[nf] = *(const bf16x8*)&Bs[(wn + 16 * nf + l15) * 40 + quad * 8];
        #pragma unroll
        for (int mf = 0; mf < 2; ++mf)
            #pragma unroll
            for (int nf = 0; nf < 2; ++nf)
                acc[mf][nf] = MFMA(af[mf], bf[nf], acc[mf][nf]);
    }
    #pragma unroll
    for (int mf = 0; mf < 2; ++mf)
        #pragma unroll
        for (int nf = 0; nf < 2; ++nf)
            #pragma unroll
            for (int r = 0; r < 4; ++r)
                Cout[(size_t)(m0 + wm + 16 * mf + 4 * quad + r) * DIM + n0 + wn + 16 * nf + l15] =
                    acc[mf][nf][r];
}

// ---------------------------------------------------------------------------
// Attention v2: 64 q-rows per block (4 waves x 16q), 1024 blocks ->
// 4 blocks/CU (27 KB LDS), 16 waves/CU = 4 waves/SIMD (was 2).
// Single-buffered K/V staging with register prefetch across the barrier
// (K/V is L2-resident: FETCH was 4% of HBM peak). Es per-wave, no barrier.
// Scores pre-scaled by log2(e)/8 (in Wq) -> e = exp2(max(s,0)).
// XCD swizzle: 4 bh per XCD (2 MB K/V working set < 4 MB L2).
// ---------------------------------------------------------------------------
__global__ __launch_bounds__(256) void attn_mfma(const short* __restrict__ Qb,
                                                 const short* __restrict__ Kb,
                                                 const short* __restrict__ Vtg,
                                                 short* __restrict__ Ob) {
    __shared__ short Ks[64 * 72];
    __shared__ short Vs[64 * 72];
    __shared__ short Es[4][16 * 72];

    const int tid = threadIdx.x;
    const int w = tid >> 6, ln = tid & 63, l15 = ln & 15, quad = ln >> 4;

    const int f = blockIdx.x;
    const int swz = ((f & 7) << 7) | (f >> 3);      // bijective, 1024 blocks
    const int qt0 = (swz & 31) * 64;
    const int bh  = swz >> 5;
    const int b = bh >> 3, h = bh & 7;
    const size_t tokbase = (size_t)b * S_LEN;

    // resident Q fragments: wave w covers q rows [qt0+16w, qt0+16w+16)
    bf16x8 qf[2];
    #pragma unroll
    for (int ks = 0; ks < 2; ++ks)
        qf[ks] = *(const bf16x8*)&Qb[(tokbase + qt0 + 16 * w + l15) * DIM +
                                     h * 64 + 32 * ks + 8 * quad];

    const int srow = tid >> 3, ssg = tid & 7;    // srow 0..31
    const short* kbase = Kb  + (tokbase + srow) * DIM + h * 64 + ssg * 8;
    const short* vbase = Vtg + ((size_t)bh * 64 + srow) * S_LEN + ssg * 8;

    // prefetch chunk 0 into regs
    bf16x8 k0r = *(const bf16x8*)kbase;
    bf16x8 k1r = *(const bf16x8*)(kbase + (size_t)32 * DIM);
    bf16x8 v0r = *(const bf16x8*)vbase;
    bf16x8 v1r = *(const bf16x8*)(vbase + (size_t)32 * S_LEN);

    f32x4 oacc[4] = {};
    f32x4 d4 = {0.f, 0.f, 0.f, 0.f};

    for (int kc = 0; kc < NCH; ++kc) {
        // stage current chunk (regs -> LDS)
        *(bf16x8*)&Ks[srow * 72 + ssg * 8] = k0r;
        *(bf16x8*)&Ks[(srow + 32) * 72 + ssg * 8] = k1r;
        *(bf16x8*)&Vs[srow * 72 + ssg * 8] = v0r;
        *(bf16x8*)&Vs[(srow + 32) * 72 + ssg * 8] = v1r;
        __syncthreads();
        if (kc + 1 < NCH) {     // prefetch next chunk into regs (L2 hit, hides under compute)
            const size_t ko = (size_t)(kc + 1) * 64 * DIM;
            const size_t vo = (size_t)(kc + 1) * 64;
            k0r = *(const bf16x8*)(kbase + ko);
            k1r = *(const bf16x8*)(kbase + ko + (size_t)32 * DIM);
            v0r = *(const bf16x8*)(vbase + vo);
            v1r = *(const bf16x8*)(vbase + vo + (size_t)32 * S_LEN);
        }

        // ---- phase 1: S^T[key][q] = K * Q^T  (64 keys x 16 q per wave) ----
        f32x4 sacc[4];
        __builtin_amdgcn_s_setprio(1);
        #pragma unroll
        for (int mf = 0; mf < 4; ++mf) {
            bf16x8 ka = *(const bf16x8*)&Ks[(16 * mf + l15) * 72 + 8 * quad];
            bf16x8 kb = *(const bf16x8*)&Ks[(16 * mf + l15) * 72 + 32 + 8 * quad];
            f32x4 s = {0.f, 0.f, 0.f, 0.f};
            s = MFMA(ka, qf[0], s);
            s = MFMA(kb, qf[1], s);
            sacc[mf] = s;
        }
        __builtin_amdgcn_s_setprio(0);

        // ---- e = exp2(max(s,0)) -> Es (per-wave, no barrier) ----
        short* Esw = &Es[w][0];
        #pragma unroll
        for (int mf = 0; mf < 4; ++mf) {
            const float e0 = fast_exp2(fmaxf(sacc[mf][0], 0.f));
            const float e1 = fast_exp2(fmaxf(sacc[mf][1], 0.f));
            const float e2 = fast_exp2(fmaxf(sacc[mf][2], 0.f));
            const float e3 = fast_exp2(fmaxf(sacc[mf][3], 0.f));
            d4[0] += e0; d4[1] += e1; d4[2] += e2; d4[3] += e3;
            uint2 p;
            p.x = cvtpk(e0, e1);
            p.y = cvtpk(e2, e3);
            *(uint2*)&Esw[l15 * 72 + 16 * mf + 4 * quad] = p;
        }

        // ---- phase 2: O[q][hd] += E * V ----
        bf16x8 e0 = *(const bf16x8*)&Esw[l15 * 72 + 8 * quad];
        bf16x8 e1 = *(const bf16x8*)&Esw[l15 * 72 + 32 + 8 * quad];
        __builtin_amdgcn_s_setprio(1);
        #pragma unroll
        for (int nf2 = 0; nf2 < 4; ++nf2) {
            bf16x8 vf0 = *(const bf16x8*)&Vs[(16 * nf2 + l15) * 72 + 8 * quad];
            bf16x8 vf1 = *(const bf16x8*)&Vs[(16 * nf2 + l15) * 72 + 32 + 8 * quad];
            oacc[nf2] = MFMA(e0, vf0, oacc[nf2]);
            oacc[nf2] = MFMA(e1, vf1, oacc[nf2]);
        }
        __builtin_amdgcn_s_setprio(0);
        __syncthreads();   // all waves done reading Ks/Vs before next overwrite
    }

    // ---- denominator: horizontal sum of 4-wide partials, then quad shfl ----
    float dsum = (d4[0] + d4[1]) + (d4[2] + d4[3]);
    dsum += __shfl_xor(dsum, 16);
    dsum += __shfl_xor(dsum, 32);
    const float dinv = 1.0f / dsum;

    // ---- normalize + store bf16 ----
    #pragma unroll
    for (int r = 0; r < 4; ++r) {
        const float di = __shfl(dinv, 4 * quad + r);   // lane l15=4q+r holds row's dinv
        const size_t rowaddr = (tokbase + qt0 + 16 * w + 4 * quad + r) * DIM + h * 64;
        #pragma unroll
        for (int nf2 = 0; nf2 < 4; ++nf2)
            Ob[rowaddr + 16 * nf2 + l15] = f2b(oacc[nf2][r] * di);
    }
}

// ---------------------------------------------------------------------------
extern "C" void kernel_launch(void* const* d_in, const int* in_sizes, int n_in,
                              void* d_out, int out_size, void* d_ws, size_t ws_size,
                              hipStream_t stream) {
    const float* X  = (const float*)d_in[0];
    const float* Y  = (const float*)d_in[1];
    const float* Z  = (const float*)d_in[2];
    const float* Wq = (const float*)d_in[3];
    const float* Wk = (const float*)d_in[4];
    // d_in[5] = Wv dead in reference forward
    const float* Wo = (const float*)d_in[6];

    char* p = (char*)d_ws;
    const size_t MD = (size_t)M_TOT * DIM;
    short* Qb  = (short*)p; p += MD * 2;
    short* Kb  = (short*)p; p += MD * 2;
    short* Vt  = (short*)p; p += MD * 2;
    short* Ob  = (short*)p; p += MD * 2;
    short* Wtq = (short*)p; p += (size_t)DIM * DIM * 2;
    short* Wtk = (short*)p; p += (size_t)DIM * DIM * 2;
    short* Wto = (short*)p; p += (size_t)DIM * DIM * 2;

    prep_wt<<<dim3(8, 8, 3), 256, 0, stream>>>(Wq, Wk, Wo, Wtq, Wtk, Wto);
    proj_gemm<<<dim3(64, 4, 3), 256, 0, stream>>>(X, Y, Z, Wtq, Wtk, Wto, Qb, Kb, Vt);
    attn_mfma<<<dim3(1024), 256, 0, stream>>>(Qb, Kb, Vt, Ob);
    out_gemm<<<dim3(1024), 256, 0, stream>>>(Ob, Wto, (float*)d_out);
}

// Round 6
// 193.652 us; speedup vs baseline: 1.1144x; 1.0526x over previous
//
#include <hip/hip_runtime.h>
#include <math.h>

#define S_LEN 2048
#define DIM   512
#define M_TOT 8192
#define NCH   (S_LEN / 64)

typedef __attribute__((ext_vector_type(8))) short bf16x8;
typedef __attribute__((ext_vector_type(4))) short bf16x4;
typedef __attribute__((ext_vector_type(4))) float f32x4;
typedef __attribute__((ext_vector_type(16))) float f32x16;

#define MFMA(a, b, c)   __builtin_amdgcn_mfma_f32_16x16x32_bf16((a), (b), (c), 0, 0, 0)
#define MFMA32(a, b, c) __builtin_amdgcn_mfma_f32_32x32x16_bf16((a), (b), (c), 0, 0, 0)

// log2(e)/8 : baked into Wq so attention scores arrive as log2(e)*s/8,
// letting softmax use exp2 directly (exp(relu(s)/8) == exp2(relu(s'))).
#define QSCALE 0.18033688011112042f

__device__ __forceinline__ short f2b(float x) {
    union { float f; unsigned u; } v; v.f = x;
    unsigned r = v.u + 0x7FFFu + ((v.u >> 16) & 1u);   // RNE
    return (short)(r >> 16);
}

// packed f32x2 -> bf16x2 (RNE), single VOP3; low half = first arg
// (order verified by the passing proj_gemm staging path).
__device__ __forceinline__ unsigned cvtpk(float a, float b) {
    unsigned r;
    asm("v_cvt_pk_bf16_f32 %0, %1, %2" : "=v"(r) : "v"(a), "v"(b));
    return r;
}

__device__ __forceinline__ bf16x8 cvt8(float4 lo, float4 hi) {
    union { unsigned u[4]; bf16x8 v; } o;
    o.u[0] = cvtpk(lo.x, lo.y);
    o.u[1] = cvtpk(lo.z, lo.w);
    o.u[2] = cvtpk(hi.x, hi.y);
    o.u[3] = cvtpk(hi.z, hi.w);
    return o.v;
}

__device__ __forceinline__ float fast_exp2(float x) {
#if __has_builtin(__builtin_amdgcn_exp2f)
    return __builtin_amdgcn_exp2f(x);
#else
    return __expf(x * 0.693147180559945f);   // exp(x*ln2) == 2^x
#endif
}

// ---------------------------------------------------------------------------
// Wt[n][k] bf16 = transpose+convert of W[k][n] f32. 64x64 tiles.
// Wq additionally scaled by QSCALE (see above).
// ---------------------------------------------------------------------------
__global__ __launch_bounds__(256) void prep_wt(const float* Wq, const float* Wk, const float* Wo,
                                               short* Wtq, short* Wtk, short* Wto) {
    const int zi = blockIdx.z;
    const float* W = zi == 0 ? Wq : zi == 1 ? Wk : Wo;
    short*      Wt = zi == 0 ? Wtq : zi == 1 ? Wtk : Wto;
    const float sc = zi == 0 ? QSCALE : 1.0f;
    __shared__ short Ts[64 * 72];
    const int t = threadIdx.x;
    const int k0 = blockIdx.x * 64, n0 = blockIdx.y * 64;
    #pragma unroll
    for (int it = 0; it < 4; ++it) {
        const int r = (t >> 4) + 16 * it;
        const int cq = t & 15;
        float4 v = *(const float4*)&W[(size_t)(k0 + r) * DIM + n0 + cq * 4];
        Ts[(4 * cq + 0) * 72 + r] = f2b(v.x * sc);
        Ts[(4 * cq + 1) * 72 + r] = f2b(v.y * sc);
        Ts[(4 * cq + 2) * 72 + r] = f2b(v.z * sc);
        Ts[(4 * cq + 3) * 72 + r] = f2b(v.w * sc);
    }
    __syncthreads();
    #pragma unroll
    for (int it = 0; it < 2; ++it) {
        const int n = (t >> 3) + 32 * it;
        const int sg = t & 7;
        *(bf16x8*)&Wt[(size_t)(n0 + n) * DIM + k0 + sg * 8] = *(const bf16x8*)&Ts[n * 72 + sg * 8];
    }
}

// ---------------------------------------------------------------------------
// Projection GEMMs (fused 3): 128x128 tile, BK=32, 4 waves (2x2, each 64x64).
// A is read as fp32 (X/Y/Z) and converted to bf16 during staging.
// zi==2 (V) is stored TRANSPOSED per (b,h): Vt[((b*8+h)*64+hd)*2048 + s].
// ---------------------------------------------------------------------------
__global__ __launch_bounds__(256) void proj_gemm(const float* __restrict__ X,
                                                 const float* __restrict__ Y,
                                                 const float* __restrict__ Z,
                                                 const short* __restrict__ Wtq,
                                                 const short* __restrict__ Wtk,
                                                 const short* __restrict__ Wto,
                                                 short* __restrict__ Qb,
                                                 short* __restrict__ Kb,
                                                 short* __restrict__ Vt) {
    const int zi = blockIdx.z;
    const float* A  = zi == 0 ? X : zi == 1 ? Y : Z;
    const short* Bw = zi == 0 ? Wtq : zi == 1 ? Wtk : Wto;

    __shared__ short As[128 * 40];
    __shared__ short Bs[128 * 40];
    const int tid = threadIdx.x;
    const int w = tid >> 6, ln = tid & 63, l15 = ln & 15, quad = ln >> 4;
    const int m0 = blockIdx.x * 128, n0 = blockIdx.y * 128;
    const int wm = (w & 1) * 64, wn = (w >> 1) * 64;

    const int r0 = tid >> 2, r1 = r0 + 64;
    const int sg = tid & 3;
    const float* ap0 = A  + (size_t)(m0 + r0) * DIM + sg * 8;
    const float* ap1 = A  + (size_t)(m0 + r1) * DIM + sg * 8;
    const short* bp0 = Bw + (size_t)(n0 + r0) * DIM + sg * 8;
    const short* bp1 = Bw + (size_t)(n0 + r1) * DIM + sg * 8;

    float4 a0l = *(const float4*)ap0, a0h = *(const float4*)(ap0 + 4);
    float4 a1l = *(const float4*)ap1, a1h = *(const float4*)(ap1 + 4);
    bf16x8 b0 = *(const bf16x8*)bp0, b1 = *(const bf16x8*)bp1;

    f32x4 acc[4][4] = {};

    for (int k0 = 0; k0 < DIM; k0 += 32) {
        __syncthreads();
        *(bf16x8*)&As[r0 * 40 + sg * 8] = cvt8(a0l, a0h);
        *(bf16x8*)&As[r1 * 40 + sg * 8] = cvt8(a1l, a1h);
        *(bf16x8*)&Bs[r0 * 40 + sg * 8] = b0;
        *(bf16x8*)&Bs[r1 * 40 + sg * 8] = b1;
        __syncthreads();
        const int kn = (k0 + 32 < DIM) ? k0 + 32 : 0;
        a0l = *(const float4*)(ap0 + kn); a0h = *(const float4*)(ap0 + kn + 4);
        a1l = *(const float4*)(ap1 + kn); a1h = *(const float4*)(ap1 + kn + 4);
        b0 = *(const bf16x8*)(bp0 + kn); b1 = *(const bf16x8*)(bp1 + kn);

        bf16x8 af[4], bf[4];
        #pragma unroll
        for (int mf = 0; mf < 4; ++mf) af[mf] = *(const bf16x8*)&As[(wm + 16 * mf + l15) * 40 + quad * 8];
        #pragma unroll
        for (int nf = 0; nf < 4; ++nf) bf[nf] = *(const bf16x8*)&Bs[(wn + 16 * nf + l15) * 40 + quad * 8];
        #pragma unroll
        for (int mf = 0; mf < 4; ++mf)
            #pragma unroll
            for (int nf = 0; nf < 4; ++nf)
                acc[mf][nf] = MFMA(af[mf], bf[nf], acc[mf][nf]);
    }

    if (zi < 2) {
        short* C = zi == 0 ? Qb : Kb;
        #pragma unroll
        for (int mf = 0; mf < 4; ++mf)
            #pragma unroll
            for (int nf = 0; nf < 4; ++nf)
                #pragma unroll
                for (int r = 0; r < 4; ++r)
                    C[(size_t)(m0 + wm + 16 * mf + 4 * quad + r) * DIM + n0 + wn + 16 * nf + l15] =
                        f2b(acc[mf][nf][r]);
    } else {
        #pragma unroll
        for (int mf = 0; mf < 4; ++mf)
            #pragma unroll
            for (int nf = 0; nf < 4; ++nf) {
                const int col = n0 + wn + 16 * nf + l15;
                const int h = col >> 6, hd = col & 63;
                const int row0_ = m0 + wm + 16 * mf + 4 * quad;
                const int bb = row0_ >> 11, s0 = row0_ & 2047;
                bf16x4 o = { f2b(acc[mf][nf][0]), f2b(acc[mf][nf][1]),
                             f2b(acc[mf][nf][2]), f2b(acc[mf][nf][3]) };
                *(bf16x4*)&Vt[((size_t)((bb * 8 + h) * 64 + hd)) * S_LEN + s0] = o;
            }
    }
}

// ---------------------------------------------------------------------------
// Final GEMM: fp32 out = Ob_bf16 @ Wto^T. 64x64 tiles, BK=32 — exact
// round-2 PASSING version (reverted to isolate the attn change).
// ---------------------------------------------------------------------------
__global__ __launch_bounds__(256) void out_gemm(const short* __restrict__ Ob,
                                                const short* __restrict__ Wto,
                                                float* __restrict__ Cout) {
    __shared__ short As[64 * 40];
    __shared__ short Bs[64 * 40];
    const int tid = threadIdx.x;
    const int w = tid >> 6, ln = tid & 63, l15 = ln & 15, quad = ln >> 4;

    const int f = blockIdx.x;
    const int swz = ((f & 7) << 7) | (f >> 3);      // bijective, 1024 blocks
    const int m0 = (swz >> 3) * 64, n0 = (swz & 7) * 64;
    const int wm = (w & 1) * 32, wn = (w >> 1) * 32;

    const int row = tid >> 2;         // 0..63
    const int sg = tid & 3;           // k sub-offset
    const short* ap = Ob  + (size_t)(m0 + row) * DIM + sg * 8;
    const short* bp = Wto + (size_t)(n0 + row) * DIM + sg * 8;

    bf16x8 a0 = *(const bf16x8*)ap, b0 = *(const bf16x8*)bp;

    f32x4 acc[2][2] = {};

    for (int k0 = 0; k0 < DIM; k0 += 32) {
        __syncthreads();
        *(bf16x8*)&As[row * 40 + sg * 8] = a0;
        *(bf16x8*)&Bs[row * 40 + sg * 8] = b0;
        __syncthreads();
        const int kn = (k0 + 32 < DIM) ? k0 + 32 : 0;
        a0 = *(const bf16x8*)(ap + kn); b0 = *(const bf16x8*)(bp + kn);

        bf16x8 af[2], bf[2];
        #pragma unroll
        for (int mf = 0; mf < 2; ++mf) af[mf] = *(const bf16x8*)&As[(wm + 16 * mf + l15) * 40 + quad * 8];
        #pragma unroll
        for (int nf = 0; nf < 2; ++nf) bf[nf] = *(const bf16x8*)&Bs[(wn + 16 * nf + l15) * 40 + quad * 8];
        #pragma unroll
        for (int mf = 0; mf < 2; ++mf)
            #pragma unroll
            for (int nf = 0; nf < 2; ++nf)
                acc[mf][nf] = MFMA(af[mf], bf[nf], acc[mf][nf]);
    }
    #pragma unroll
    for (int mf = 0; mf < 2; ++mf)
        #pragma unroll
        for (int nf = 0; nf < 2; ++nf)
            #pragma unroll
            for (int r = 0; r < 4; ++r)
                Cout[(size_t)(m0 + wm + 16 * mf + 4 * quad + r) * DIM + n0 + wn + 16 * nf + l15] =
                    acc[mf][nf][r];
}

// ---------------------------------------------------------------------------
// Attention v6: 32x32x16 MFMA, 128q/block (4 waves x 32q), 512 blocks.
// NO cross-lane exchange at all: PV MFMA #m consumes exactly the keys each
// lane already holds in its QK^T C/D regs, i.e. pf[m] = [cp[2m], cp[2m+1],
// cp[2m+8], cp[2m+9]] (pure register renaming). pf position (hL,j) then
// holds key 8m + 4hL + (j&3) + 32*(j>>2); V is staged into LDS with the SAME
// column permutation: storage col 16m+8hL+e <- key 8m+4hL+(e&3)+32*(e>>2).
// Correctness rests only on (a) the HW-verified 32x32 C/D formula (proven in
// this kernel by the O-store rows) and (b) kappa_A == kappa_B positional
// pairing (proven by QK^T being correct).
// K/V double-buffered, 1 barrier/chunk. All LDS strides 72.
// ---------------------------------------------------------------------------
__global__ __launch_bounds__(256) void attn_mfma(const short* __restrict__ Qb,
                                                 const short* __restrict__ Kb,
                                                 const short* __restrict__ Vtg,
                                                 short* __restrict__ Ob) {
    __shared__ short Ks[2][64 * 72];   // [key][d]
    __shared__ short Vs[2][64 * 72];   // [hd][perm-col]  (from pre-transposed Vt)
    __shared__ float Ds[4][32];

    const int tid = threadIdx.x;
    const int w = tid >> 6, ln = tid & 63, n31 = ln & 31, hL = ln >> 5;

    const int f = blockIdx.x;                     // 512 blocks
    const int swz = ((f & 7) << 6) | (f >> 3);    // bijective; 4 bh per XCD
    const int qt0 = (swz & 15) * 128;
    const int bh  = swz >> 4;
    const int b = bh >> 3, h = bh & 7;
    const size_t tokbase = (size_t)b * S_LEN;

    // Q as B-operand, resident: wave w covers q rows [qt0+32w, +32)
    const int q0w = qt0 + 32 * w;
    bf16x8 qf[4];
    #pragma unroll
    for (int dk = 0; dk < 4; ++dk)
        qf[dk] = *(const bf16x8*)&Qb[(tokbase + q0w + n31) * DIM + h * 64 + 16 * dk + 8 * hL];

    const int srow = tid >> 2, sg = tid & 3;      // srow 0..63
    const short* kbase = Kb  + (tokbase + srow) * DIM + h * 64 + sg * 16;
    // V: srow = hd row; this thread gathers keys {8sg..8sg+7} and
    // {32+8sg..32+8sg+7} of the chunk (see column permutation above).
    const short* vbase = Vtg + ((size_t)bh * 64 + srow) * S_LEN;

    union b8split { bf16x8 v; struct { bf16x4 lo, hi; } s; };

    bf16x8 kr0, kr1;
    b8split vrA, vrB;

    f32x16 oacc[2] = {};
    f32x4 d4 = {0.f, 0.f, 0.f, 0.f};

    // prologue: chunk0 -> buf0; prefetch chunk1 regs
    kr0 = *(const bf16x8*)kbase;       kr1 = *(const bf16x8*)(kbase + 8);
    vrA.v = *(const bf16x8*)(vbase + 8 * sg);
    vrB.v = *(const bf16x8*)(vbase + 32 + 8 * sg);
    *(bf16x8*)&Ks[0][srow * 72 + sg * 16]     = kr0;
    *(bf16x8*)&Ks[0][srow * 72 + sg * 16 + 8] = kr1;
    {
        short* vrow = &Vs[0][srow * 72 + 16 * sg];
        *(bf16x4*)&vrow[0]  = vrA.s.lo;  *(bf16x4*)&vrow[8]  = vrA.s.hi;
        *(bf16x4*)&vrow[4]  = vrB.s.lo;  *(bf16x4*)&vrow[12] = vrB.s.hi;
    }
    kr0 = *(const bf16x8*)(kbase + (size_t)64 * DIM);
    kr1 = *(const bf16x8*)(kbase + (size_t)64 * DIM + 8);
    vrA.v = *(const bf16x8*)(vbase + 64 + 8 * sg);
    vrB.v = *(const bf16x8*)(vbase + 64 + 32 + 8 * sg);
    __syncthreads();

    for (int kc = 0; kc < NCH; ++kc) {
        const int cur = kc & 1;
        if (kc + 1 < NCH) {     // stage chunk kc+1 (regs) into other buffer
            *(bf16x8*)&Ks[cur ^ 1][srow * 72 + sg * 16]     = kr0;
            *(bf16x8*)&Ks[cur ^ 1][srow * 72 + sg * 16 + 8] = kr1;
            short* vrow = &Vs[cur ^ 1][srow * 72 + 16 * sg];
            *(bf16x4*)&vrow[0]  = vrA.s.lo;  *(bf16x4*)&vrow[8]  = vrA.s.hi;
            *(bf16x4*)&vrow[4]  = vrB.s.lo;  *(bf16x4*)&vrow[12] = vrB.s.hi;
        }
        if (kc + 2 < NCH) {     // prefetch chunk kc+2 into regs (L2-resident)
            const size_t ko = (size_t)(kc + 2) * 64 * DIM;
            const size_t vo = (size_t)(kc + 2) * 64;
            kr0 = *(const bf16x8*)(kbase + ko);
            kr1 = *(const bf16x8*)(kbase + ko + 8);
            vrA.v = *(const bf16x8*)(vbase + vo + 8 * sg);
            vrB.v = *(const bf16x8*)(vbase + vo + 32 + 8 * sg);
        }

        // ---- phase 1: S^T[key][q] = K * Q^T (2 key-tiles of 32 x 32 q) ----
        f32x16 sacc[2] = {};
        __builtin_amdgcn_s_setprio(1);
        #pragma unroll
        for (int kt = 0; kt < 2; ++kt)
            #pragma unroll
            for (int dk = 0; dk < 4; ++dk) {
                bf16x8 ka = *(const bf16x8*)&Ks[cur][(32 * kt + n31) * 72 + 16 * dk + 8 * hL];
                sacc[kt] = MFMA32(ka, qf[dk], sacc[kt]);
            }
        __builtin_amdgcn_s_setprio(0);

        // ---- e = exp2(max(s,0)), pack to bf16 pairs (lane-local, q = n31).
        // cp[8kt+p] = keys 32kt + 4hL + {0,1|2,3|8,9|10,11|16,...} per p. ----
        unsigned cp[16];
        #pragma unroll
        for (int kt = 0; kt < 2; ++kt)
            #pragma unroll
            for (int p = 0; p < 8; ++p) {
                const float e0 = fast_exp2(fmaxf(sacc[kt][2 * p], 0.f));
                const float e1 = fast_exp2(fmaxf(sacc[kt][2 * p + 1], 0.f));
                d4[p & 3] += e0 + e1;
                cp[8 * kt + p] = cvtpk(e0, e1);
            }

        // ---- phase 2: O[q][hd] += P * V, 4 MFMAs over key-subsets.
        // pf[m] = pure register renaming of the lane's own C/D words. ----
        __builtin_amdgcn_s_setprio(1);
        #pragma unroll
        for (int m = 0; m < 4; ++m) {
            union { unsigned u[4]; bf16x8 v; } pu;
            pu.u[0] = cp[2 * m];     pu.u[1] = cp[2 * m + 1];
            pu.u[2] = cp[2 * m + 8]; pu.u[3] = cp[2 * m + 9];
            #pragma unroll
            for (int nt = 0; nt < 2; ++nt) {
                bf16x8 vb = *(const bf16x8*)&Vs[cur][(32 * nt + n31) * 72 + 16 * m + 8 * hL];
                oacc[nt] = MFMA32(pu.v, vb, oacc[nt]);
            }
        }
        __builtin_amdgcn_s_setprio(0);
        __syncthreads();   // staged writes visible; readers done before overwrite
    }

    // ---- denominator: lane-local partials + one half-exchange ----
    float dtot = (d4[0] + d4[1]) + (d4[2] + d4[3]);
    dtot += __shfl_xor(dtot, 32);
    const float dinv = 1.0f / dtot;
    if (ln < 32) Ds[w][n31] = dinv;
    __syncthreads();
    f32x4 dv[4];
    #pragma unroll
    for (int g = 0; g < 4; ++g)
        dv[g] = *(const f32x4*)&Ds[w][8 * g + 4 * hL];

    // ---- normalize + store bf16 ----
    #pragma unroll
    for (int nt = 0; nt < 2; ++nt)
        #pragma unroll
        for (int r = 0; r < 16; ++r) {
            const int qb = 32 * w + 4 * hL + 8 * (r >> 2) + (r & 3);
            Ob[(tokbase + qt0 + qb) * DIM + h * 64 + 32 * nt + n31] =
                f2b(oacc[nt][r] * dv[r >> 2][r & 3]);
        }
}

// ---------------------------------------------------------------------------
extern "C" void kernel_launch(void* const* d_in, const int* in_sizes, int n_in,
                              void* d_out, int out_size, void* d_ws, size_t ws_size,
                              hipStream_t stream) {
    const float* X  = (const float*)d_in[0];
    const float* Y  = (const float*)d_in[1];
    const float* Z  = (const float*)d_in[2];
    const float* Wq = (const float*)d_in[3];
    const float* Wk = (const float*)d_in[4];
    // d_in[5] = Wv dead in reference forward
    const float* Wo = (const float*)d_in[6];

    char* p = (char*)d_ws;
    const size_t MD = (size_t)M_TOT * DIM;
    short* Qb  = (short*)p; p += MD * 2;
    short* Kb  = (short*)p; p += MD * 2;
    short* Vt  = (short*)p; p += MD * 2;
    short* Ob  = (short*)p; p += MD * 2;
    short* Wtq = (short*)p; p += (size_t)DIM * DIM * 2;
    short* Wtk = (short*)p; p += (size_t)DIM * DIM * 2;
    short* Wto = (short*)p; p += (size_t)DIM * DIM * 2;

    prep_wt<<<dim3(8, 8, 3), 256, 0, stream>>>(Wq, Wk, Wo, Wtq, Wtk, Wto);
    proj_gemm<<<dim3(64, 4, 3), 256, 0, stream>>>(X, Y, Z, Wtq, Wtk, Wto, Qb, Kb, Vt);
    attn_mfma<<<dim3(512), 256, 0, stream>>>(Qb, Kb, Vt, Ob);
    out_gemm<<<dim3(1024), 256, 0, stream>>>(Ob, Wto, (float*)d_out);
}